// Round 1
// baseline (399.539 us; speedup 1.0000x reference)
//
#include <hip/hip_runtime.h>

typedef unsigned short u16;
typedef __bf16 bf16x8 __attribute__((ext_vector_type(8)));
typedef float f32x4 __attribute__((ext_vector_type(4)));

#define D 64
#define LPITCH 136   // 128 + 8 bf16 pad
#define CCAP 1280    // LDS edge-list capacity per 64-node tile (mean ~1024, +2 sigma)
#define PGRID 1024   // grid for edge-pass kernels (4 blocks/CU -> 16 waves/CU)

__device__ __forceinline__ float b2f(u16 u) {
    unsigned v = ((unsigned)u) << 16;
    float f;
    __builtin_memcpy(&f, &v, 4);
    return f;
}
__device__ __forceinline__ float u2f_lo(unsigned u) {
    unsigned v = u << 16;
    float f;
    __builtin_memcpy(&f, &v, 4);
    return f;
}
__device__ __forceinline__ float u2f_hi(unsigned u) {
    unsigned v = u & 0xFFFF0000u;
    float f;
    __builtin_memcpy(&f, &v, 4);
    return f;
}
__device__ __forceinline__ u16 f2b(float f) {
    unsigned u;
    __builtin_memcpy(&u, &f, 4);
    u = u + 0x7FFFu + ((u >> 16) & 1u);   // RNE
    return (u16)(u >> 16);
}
__device__ __forceinline__ bf16x8 ld_frag(const u16* p) {
    union { uint4 u; bf16x8 b; } cv;
    cv.u = *(const uint4*)p;
    return cv.b;
}

// ---------------- prep: degree count (global atomics) + cvt/weight-prep tails ------
__global__ __launch_bounds__(256) void prep_kernel(const int* __restrict__ dst, int E,
                                                   int* __restrict__ deg,
                                                   const float* __restrict__ xf,
                                                   u16* __restrict__ xb, int total4,
                                                   const float* __restrict__ wl,
                                                   const float* __restrict__ wr,
                                                   const float* __restrict__ wres,
                                                   const float* __restrict__ wfc,
                                                   u16* __restrict__ WtL,
                                                   u16* __restrict__ WresT,
                                                   u16* __restrict__ WfcT,
                                                   int* __restrict__ row_ptr, int N) {
    int gid = blockIdx.x * 256 + threadIdx.x;
    int gstr = PGRID * 256;
    if (gid == 0) row_ptr[N] = E;

    // degree histogram: 100K random counters, L2-resident -> cheap global atomics
    int e4 = E >> 2;
    for (int i = gid; i < e4; i += gstr) {
        int4 d = *(const int4*)(dst + i * 4);
        atomicAdd(&deg[d.x], 1);
        atomicAdd(&deg[d.y], 1);
        atomicAdd(&deg[d.z], 1);
        atomicAdd(&deg[d.w], 1);
    }
    for (int i = e4 * 4 + gid; i < E; i += gstr) atomicAdd(&deg[dst[i]], 1);

    // x f32 -> bf16
    for (int i = gid; i < total4; i += gstr) {
        float4 v = *(const float4*)(xf + i * 4);
        ushort4 o;
        o.x = f2b(v.x); o.y = f2b(v.y); o.z = f2b(v.z); o.w = f2b(v.w);
        *(ushort4*)(xb + i * 4) = o;
    }
    // W^T prep: [L][64 rows][128 cols] = concat(w_l^T, w_r^T)
    for (int idx = gid; idx < 3 * 64 * 128; idx += gstr) {
        int l = idx >> 13;
        int rem = idx & 8191;
        int n = rem >> 7;
        int k = rem & 127;
        float v = (k < 64) ? wl[l * 4096 + k * 64 + n] : wr[l * 4096 + (k - 64) * 64 + n];
        WtL[idx] = f2b(v);
    }
    for (int idx = gid; idx < 4096; idx += gstr) {
        int n = idx >> 6, k = idx & 63;
        WresT[idx] = f2b(wres[k * 64 + n]);
        WfcT[idx] = f2b(wfc[k * 64 + n]);
    }
}

// ---------------- scanA: per-1024-block sums of deg ---------------------------------
__global__ __launch_bounds__(256) void scanA_kernel(const int* __restrict__ deg,
                                                    int* __restrict__ bsum, int N) {
    __shared__ int red[256];
    int b = blockIdx.x, t = threadIdx.x;
    int base = b * 1024 + t * 4;
    int s = 0;
    if (base + 3 < N) {
        int4 v = *(const int4*)(deg + base);
        s = v.x + v.y + v.z + v.w;
    } else {
        for (int k = 0; k < 4; k++)
            if (base + k < N) s += deg[base + k];
    }
    red[t] = s;
    __syncthreads();
    for (int off = 128; off > 0; off >>= 1) {
        if (t < off) red[t] += red[t + off];
        __syncthreads();
    }
    if (t == 0) bsum[b] = red[0];
}

// ---------------- scanB: exclusive scan of block sums (nb <= 256) -------------------
__global__ __launch_bounds__(256) void scanB_kernel(int* __restrict__ bsum, int nb) {
    __shared__ int ss[256];
    int t = threadIdx.x;
    int v = (t < nb) ? bsum[t] : 0;
    ss[t] = v;
    __syncthreads();
    for (int off = 1; off < 256; off <<= 1) {
        int u = (t >= off) ? ss[t - off] : 0;
        __syncthreads();
        ss[t] += u;
        __syncthreads();
    }
    if (t < nb) bsum[t] = ss[t] - v;   // exclusive
}

// ---------------- scanC: block-local scan + offset -> row_ptr/cursor/inv_deg --------
__global__ __launch_bounds__(256) void scanC_kernel(const int* __restrict__ deg,
                                                    const int* __restrict__ bsum,
                                                    int* __restrict__ row_ptr,
                                                    int* __restrict__ cursor,
                                                    float* __restrict__ inv_deg, int N) {
    __shared__ int ss[256];
    int b = blockIdx.x, t = threadIdx.x;
    int base = b * 1024 + t * 4;
    int d0 = 0, d1 = 0, d2 = 0, d3 = 0;
    bool full = (base + 3 < N);
    if (full) {
        int4 v = *(const int4*)(deg + base);
        d0 = v.x; d1 = v.y; d2 = v.z; d3 = v.w;
    } else {
        if (base < N) d0 = deg[base];
        if (base + 1 < N) d1 = deg[base + 1];
        if (base + 2 < N) d2 = deg[base + 2];
        if (base + 3 < N) d3 = deg[base + 3];
    }
    int s = d0 + d1 + d2 + d3;
    ss[t] = s;
    __syncthreads();
    for (int off = 1; off < 256; off <<= 1) {
        int u = (t >= off) ? ss[t - off] : 0;
        __syncthreads();
        ss[t] += u;
        __syncthreads();
    }
    int p0 = bsum[b] + ss[t] - s;
    int p1 = p0 + d0, p2 = p1 + d1, p3 = p2 + d2;
    if (full) {
        *(int4*)(row_ptr + base) = make_int4(p0, p1, p2, p3);
        *(int4*)(cursor + base) = make_int4(p0, p1, p2, p3);
        float4 iv;
        iv.x = d0 > 0 ? 1.0f / (float)d0 : 0.0f;
        iv.y = d1 > 0 ? 1.0f / (float)d1 : 0.0f;
        iv.z = d2 > 0 ? 1.0f / (float)d2 : 0.0f;
        iv.w = d3 > 0 ? 1.0f / (float)d3 : 0.0f;
        *(float4*)(inv_deg + base) = iv;
    } else {
        int pp[4] = {p0, p1, p2, p3};
        int dd[4] = {d0, d1, d2, d3};
        for (int k = 0; k < 4; k++) {
            if (base + k < N) {
                row_ptr[base + k] = pp[k];
                cursor[base + k] = pp[k];
                inv_deg[base + k] = dd[k] > 0 ? 1.0f / (float)dd[k] : 0.0f;
            }
        }
    }
}

// ---------------- scatter: col[cursor[dst]++] = src ---------------------------------
__global__ __launch_bounds__(256) void scat_kernel(const int* __restrict__ src,
                                                   const int* __restrict__ dst, int E,
                                                   int* __restrict__ cursor,
                                                   int* __restrict__ col) {
    int gid = blockIdx.x * 256 + threadIdx.x;
    int gstr = PGRID * 256;
    int e4 = E >> 2;
    for (int i = gid; i < e4; i += gstr) {
        int4 s = *(const int4*)(src + i * 4);
        int4 d = *(const int4*)(dst + i * 4);
        int p0 = atomicAdd(&cursor[d.x], 1);
        col[p0] = s.x;
        int p1 = atomicAdd(&cursor[d.y], 1);
        col[p1] = s.y;
        int p2 = atomicAdd(&cursor[d.z], 1);
        col[p2] = s.z;
        int p3 = atomicAdd(&cursor[d.w], 1);
        col[p3] = s.w;
    }
    for (int i = e4 * 4 + gid; i < E; i += gstr) {
        int p = atomicAdd(&cursor[dst[i]], 1);
        col[p] = src[i];
    }
}

// ---------------- fused SAGE layer: gather-mean + GEMM + LN + ReLU + residual --------
// R9 static-slot gather (best measured) + tile edge-list staged to LDS (lcol):
// the tile's col range [rp[0],rp[64]) is contiguous -> coalesced load, then gather
// reads indices from LDS instead of dependent global col loads. Fallback to global
// col for the rare tile with >CCAP edges (uniform branch).
__global__ __launch_bounds__(256, 4) void layer_kernel(const u16* __restrict__ xb_in,
                                                       const int* __restrict__ row_ptr,
                                                       const int* __restrict__ col,
                                                       const float* __restrict__ inv_deg,
                                                       const u16* __restrict__ Wt,    // [64][128]
                                                       const float* __restrict__ bl,
                                                       const float* __restrict__ gam,
                                                       const float* __restrict__ bet,
                                                       const u16* __restrict__ WresT, // [64][64]
                                                       const float* __restrict__ bres,
                                                       const u16* __restrict__ WfcT,  // [64][64]
                                                       const float* __restrict__ bfc,
                                                       u16* __restrict__ xb_out,
                                                       float* __restrict__ fout,
                                                       int N, int layer0, int final_) {
    __shared__ __align__(16) u16 sA[64 * LPITCH];
    __shared__ __align__(16) u16 sB[64 * LPITCH];   // weights; reused as f32 stage in final
    __shared__ int lcol[CCAP];
    __shared__ int rp[65];
    __shared__ float ideg[64];
    int tid = threadIdx.x;
    int base = blockIdx.x * 64;
    int lane = tid & 63;
    int w = tid >> 6;

    // stage B (W^T rows), 4 uint4 per thread
#pragma unroll
    for (int i = 0; i < 4; i++) {
        int idx = i * 256 + tid;
        int r = idx >> 4, c = idx & 15;
        *(uint4*)&sB[r * LPITCH + c * 8] = *(const uint4*)(Wt + idx * 8);
    }
    // stage x rows into sA cols 64..127, 2 uint4 per thread
#pragma unroll
    for (int i = 0; i < 2; i++) {
        int idx = i * 256 + tid;
        int r = idx >> 3, c = idx & 7;
        int node = base + r;
        uint4 v = make_uint4(0, 0, 0, 0);
        if (node < N) v = *(const uint4*)(xb_in + node * D + c * 8);
        *(uint4*)&sA[r * LPITCH + 64 + c * 8] = v;
    }
    if (tid < 65) rp[tid] = row_ptr[min(base + tid, N)];
    if (tid < 64) ideg[tid] = (base + tid < N) ? inv_deg[base + tid] : 0.f;
    __syncthreads();

    int e0 = rp[0];
    int tileE = rp[64] - e0;
    bool fits = tileE <= CCAP;
    if (fits) {
        for (int i = tid; i < tileE; i += 256) lcol[i] = col[e0 + i];
    }
    __syncthreads();

    // gather stage: slot-per-node, 2 rounds x 8 slots per wave = 16 nodes/wave
    int slot = lane >> 3;
    int chunk = lane & 7;
    auto run_gather = [&](auto LD) {
#pragma unroll
        for (int r = 0; r < 2; r++) {
            int node_l = w * 16 + r * 8 + slot;
            float a0 = 0, a1 = 0, a2 = 0, a3 = 0, a4 = 0, a5 = 0, a6 = 0, a7 = 0;
            int e = rp[node_l], end = rp[node_l + 1];
#define ACC(v)                                          \
    a0 += u2f_lo(v.x); a1 += u2f_hi(v.x);               \
    a2 += u2f_lo(v.y); a3 += u2f_hi(v.y);               \
    a4 += u2f_lo(v.z); a5 += u2f_hi(v.z);               \
    a6 += u2f_lo(v.w); a7 += u2f_hi(v.w);
            for (; e + 7 < end; e += 8) {
                int s0 = LD(e),     s1 = LD(e + 1), s2 = LD(e + 2), s3 = LD(e + 3);
                int s4 = LD(e + 4), s5 = LD(e + 5), s6 = LD(e + 6), s7 = LD(e + 7);
                uint4 v0 = *(const uint4*)(xb_in + s0 * D + chunk * 8);
                uint4 v1 = *(const uint4*)(xb_in + s1 * D + chunk * 8);
                uint4 v2 = *(const uint4*)(xb_in + s2 * D + chunk * 8);
                uint4 v3 = *(const uint4*)(xb_in + s3 * D + chunk * 8);
                uint4 v4 = *(const uint4*)(xb_in + s4 * D + chunk * 8);
                uint4 v5 = *(const uint4*)(xb_in + s5 * D + chunk * 8);
                uint4 v6 = *(const uint4*)(xb_in + s6 * D + chunk * 8);
                uint4 v7 = *(const uint4*)(xb_in + s7 * D + chunk * 8);
                ACC(v0) ACC(v1) ACC(v2) ACC(v3)
                ACC(v4) ACC(v5) ACC(v6) ACC(v7)
            }
            if (e + 3 < end) {
                int s0 = LD(e), s1 = LD(e + 1), s2 = LD(e + 2), s3 = LD(e + 3);
                uint4 v0 = *(const uint4*)(xb_in + s0 * D + chunk * 8);
                uint4 v1 = *(const uint4*)(xb_in + s1 * D + chunk * 8);
                uint4 v2 = *(const uint4*)(xb_in + s2 * D + chunk * 8);
                uint4 v3 = *(const uint4*)(xb_in + s3 * D + chunk * 8);
                ACC(v0) ACC(v1) ACC(v2) ACC(v3)
                e += 4;
            }
            if (e + 1 < end) {
                int s0 = LD(e), s1 = LD(e + 1);
                uint4 v0 = *(const uint4*)(xb_in + s0 * D + chunk * 8);
                uint4 v1 = *(const uint4*)(xb_in + s1 * D + chunk * 8);
                ACC(v0) ACC(v1)
                e += 2;
            }
            if (e < end) {
                int s0 = LD(e);
                uint4 v0 = *(const uint4*)(xb_in + s0 * D + chunk * 8);
                ACC(v0)
            }
#undef ACC
            float m = ideg[node_l];
            uint4 o;
            o.x = (unsigned)f2b(a0 * m) | ((unsigned)f2b(a1 * m) << 16);
            o.y = (unsigned)f2b(a2 * m) | ((unsigned)f2b(a3 * m) << 16);
            o.z = (unsigned)f2b(a4 * m) | ((unsigned)f2b(a5 * m) << 16);
            o.w = (unsigned)f2b(a6 * m) | ((unsigned)f2b(a7 * m) << 16);
            *(uint4*)&sA[node_l * LPITCH + chunk * 8] = o;
        }
    };
    if (fits) run_gather([&](int e) { return lcol[e - e0]; });
    else      run_gather([&](int e) { return col[e]; });
    __syncthreads();

    // GEMM stage
    int q = lane >> 4;
    int ln = lane & 15;
    f32x4 acc[4] = {{0, 0, 0, 0}, {0, 0, 0, 0}, {0, 0, 0, 0}, {0, 0, 0, 0}};
    f32x4 accr[4] = {{0, 0, 0, 0}, {0, 0, 0, 0}, {0, 0, 0, 0}, {0, 0, 0, 0}};
    const u16* aRow = &sA[(w * 16 + ln) * LPITCH];

#pragma unroll
    for (int c = 0; c < 4; c++) {       // K = 128
        bf16x8 a = ld_frag(&aRow[c * 32 + q * 8]);
#pragma unroll
        for (int t = 0; t < 4; t++) {
            bf16x8 b = ld_frag(&sB[(t * 16 + ln) * LPITCH + c * 32 + q * 8]);
            acc[t] = __builtin_amdgcn_mfma_f32_16x16x32_bf16(a, b, acc[t], 0, 0, 0);
        }
    }
    if (layer0) {                       // residual = x @ w_res (one-shot global loads)
#pragma unroll
        for (int c = 0; c < 2; c++) {
            bf16x8 a = ld_frag(&aRow[64 + c * 32 + q * 8]);
#pragma unroll
            for (int t = 0; t < 4; t++) {
                bf16x8 b = ld_frag(WresT + (t * 16 + ln) * 64 + c * 32 + q * 8);
                accr[t] = __builtin_amdgcn_mfma_f32_16x16x32_bf16(a, b, accr[t], 0, 0, 0);
            }
        }
    }

    float bcol[4], gcol[4], btcol[4], brcol[4];
#pragma unroll
    for (int t = 0; t < 4; t++) {
        int colI = t * 16 + ln;
        bcol[t] = bl[colI];
        gcol[t] = gam[colI];
        btcol[t] = bet[colI];
        brcol[t] = layer0 ? bres[colI] : 0.f;
    }
#pragma unroll
    for (int t = 0; t < 4; t++)
#pragma unroll
        for (int r = 0; r < 4; r++) acc[t][r] += bcol[t];

    float ps[4], pq[4];
#pragma unroll
    for (int r = 0; r < 4; r++) {
        float s = 0, s2 = 0;
#pragma unroll
        for (int t = 0; t < 4; t++) { float h = acc[t][r]; s += h; s2 += h * h; }
        ps[r] = s; pq[r] = s2;
    }
    for (int off = 1; off < 16; off <<= 1) {
#pragma unroll
        for (int r = 0; r < 4; r++) {
            ps[r] += __shfl_xor(ps[r], off, 64);
            pq[r] += __shfl_xor(pq[r], off, 64);
        }
    }
    // epilogue -> sA cols 0..63 (wave-local rows; in-wave LDS dep, no barrier)
#pragma unroll
    for (int r = 0; r < 4; r++) {
        int nb = w * 16 + q * 4 + r;
        float mu = ps[r] * (1.f / 64.f);
        float var = pq[r] * (1.f / 64.f) - mu * mu;
        var = var < 0.f ? 0.f : var;
        float rstd = rsqrtf(var + 1e-5f);
#pragma unroll
        for (int t = 0; t < 4; t++) {
            int colI = t * 16 + ln;
            float hn = (acc[t][r] - mu) * rstd * gcol[t] + btcol[t];
            hn = hn > 0.f ? hn : 0.f;
            float res = layer0 ? (accr[t][r] + brcol[t])
                               : b2f(sA[nb * LPITCH + 64 + colI]);
            sA[nb * LPITCH + colI] = f2b(hn + res);
        }
    }

    if (final_) {
        // FC: out = x3 @ w_fc + b_fc; stage f32 through sB (dead after GEMM) for
        // coalesced float4 writeback. Pitch 68 floats breaks bank aliasing.
        f32x4 accf[4] = {{0, 0, 0, 0}, {0, 0, 0, 0}, {0, 0, 0, 0}, {0, 0, 0, 0}};
#pragma unroll
        for (int c = 0; c < 2; c++) {
            bf16x8 a = ld_frag(&aRow[c * 32 + q * 8]);
#pragma unroll
            for (int t = 0; t < 4; t++) {
                bf16x8 b = ld_frag(WfcT + (t * 16 + ln) * 64 + c * 32 + q * 8);
                accf[t] = __builtin_amdgcn_mfma_f32_16x16x32_bf16(a, b, accf[t], 0, 0, 0);
            }
        }
        __syncthreads();               // all waves done reading sB
        float* fB = (float*)sB;        // 64 rows x pitch 68 = 4352 floats = 17408 B
#pragma unroll
        for (int r = 0; r < 4; r++) {
            int nb = w * 16 + q * 4 + r;
#pragma unroll
            for (int t = 0; t < 4; t++) {
                int colI = t * 16 + ln;
                fB[nb * 68 + colI] = accf[t][r] + bfc[colI];
            }
        }
        __syncthreads();
#pragma unroll
        for (int i = 0; i < 4; i++) {
            int idx = i * 256 + tid;
            int row = idx >> 4, cc = idx & 15;
            int node = base + row;
            if (node < N)
                *(float4*)(fout + node * D + cc * 4) = *(const float4*)&fB[row * 68 + cc * 4];
        }
    } else {
        // coalesced writeback of this wave's 16 rows (2 uint4 per thread)
#pragma unroll
        for (int i = 0; i < 2; i++) {
            int idx = i * 64 + lane;
            int row = w * 16 + (idx >> 3);
            int ch = idx & 7;
            int node = base + row;
            if (node < N)
                *(uint4*)(xb_out + node * D + ch * 8) = *(const uint4*)&sA[row * LPITCH + ch * 8];
        }
    }
}

extern "C" void kernel_launch(void* const* d_in, const int* in_sizes, int n_in,
                              void* d_out, int out_size, void* d_ws, size_t ws_size,
                              hipStream_t stream) {
    const float* x_in = (const float*)d_in[0];
    const int* e_src = (const int*)d_in[1];
    const int* e_dst = (const int*)d_in[2];
    const float* w_l = (const float*)d_in[3];
    const float* b_l = (const float*)d_in[4];
    const float* w_r = (const float*)d_in[5];
    const float* gam = (const float*)d_in[6];
    const float* bet = (const float*)d_in[7];
    const float* w_res = (const float*)d_in[8];
    const float* b_res = (const float*)d_in[9];
    const float* w_fc = (const float*)d_in[10];
    const float* b_fc = (const float*)d_in[11];
    float* out = (float*)d_out;

    const int N = in_sizes[0] / D;
    const int E = in_sizes[1];
    const int nb = (N + 1023) / 1024;          // scan blocks (<=256 for N<=262144)

    size_t o = 0;
    auto carve = [&](size_t bytes) {
        size_t cur = o;
        o += (bytes + 255) & ~(size_t)255;
        return (char*)d_ws + cur;
    };
    int* row_ptr = (int*)carve((size_t)(N + 1) * 4);
    float* inv_deg = (float*)carve((size_t)N * 4);
    int* colA = (int*)carve((size_t)E * 4);
    int* deg = (int*)carve((size_t)N * 4);
    int* cursor = (int*)carve((size_t)N * 4);
    int* bsum = (int*)carve(256 * 4);
    u16* WtL = (u16*)carve(3 * 64 * 128 * 2);
    u16* WresT = (u16*)carve(64 * 64 * 2);
    u16* WfcT = (u16*)carve(64 * 64 * 2);
    u16* xbA = (u16*)carve((size_t)N * D * 2);
    u16* xbB = (u16*)carve((size_t)N * D * 2);

    // CSR build: global-atomic degree -> 3-kernel scan -> atomic scatter.
    // All edge passes at PGRID=1024 blocks (16 waves/CU) vs old 256/196-block bins.
    hipMemsetAsync(deg, 0, (size_t)N * 4, stream);
    prep_kernel<<<PGRID, 256, 0, stream>>>(e_dst, E, deg,
                                           x_in, xbA, N * D / 4,
                                           w_l, w_r, w_res, w_fc, WtL, WresT, WfcT,
                                           row_ptr, N);
    scanA_kernel<<<nb, 256, 0, stream>>>(deg, bsum, N);
    scanB_kernel<<<1, 256, 0, stream>>>(bsum, nb);
    scanC_kernel<<<nb, 256, 0, stream>>>(deg, bsum, row_ptr, cursor, inv_deg, N);
    scat_kernel<<<PGRID, 256, 0, stream>>>(e_src, e_dst, E, cursor, colA);

    int gridT = (N + 63) / 64;

    // layer 0: xbA -> xbB  (residual via w_res MFMA)
    layer_kernel<<<gridT, 256, 0, stream>>>(xbA, row_ptr, colA, inv_deg, WtL,
                                            b_l, gam, bet, WresT, b_res,
                                            WfcT, b_fc, xbB, out, N, 1, 0);
    // layer 1: xbB -> xbA
    layer_kernel<<<gridT, 256, 0, stream>>>(xbB, row_ptr, colA, inv_deg, WtL + 8192,
                                            b_l + 64, gam + 64, bet + 64, WresT, b_res,
                                            WfcT, b_fc, xbA, out, N, 0, 0);
    // layer 2 + fused fc: xbA -> out (f32)
    layer_kernel<<<gridT, 256, 0, stream>>>(xbA, row_ptr, colA, inv_deg, WtL + 16384,
                                            b_l + 128, gam + 128, bet + 128, WresT, b_res,
                                            WfcT, b_fc, xbB, out, N, 0, 1);
}

// Round 2
// 269.399 us; speedup vs baseline: 1.4831x; 1.4831x over previous
//
#include <hip/hip_runtime.h>

typedef unsigned short u16;
typedef __bf16 bf16x8 __attribute__((ext_vector_type(8)));
typedef float f32x4 __attribute__((ext_vector_type(4)));

#define D 64
#define LPITCH 136   // 128 + 8 bf16 pad
#define CHUNKS 512   // edge-array partitions (2 blocks/CU)
#define BSHIFT 8     // 256 nodes per bucket -> nbuck = 391 blocks for N=100000
#define CCAP 1280    // LDS edge-list capacity per 64-node tile (mean ~1024, +2 sigma)
#define TGRID 1024   // tails kernel grid (4 blocks/CU)

__device__ __forceinline__ float b2f(u16 u) {
    unsigned v = ((unsigned)u) << 16;
    float f;
    __builtin_memcpy(&f, &v, 4);
    return f;
}
__device__ __forceinline__ float u2f_lo(unsigned u) {
    unsigned v = u << 16;
    float f;
    __builtin_memcpy(&f, &v, 4);
    return f;
}
__device__ __forceinline__ float u2f_hi(unsigned u) {
    unsigned v = u & 0xFFFF0000u;
    float f;
    __builtin_memcpy(&f, &v, 4);
    return f;
}
__device__ __forceinline__ u16 f2b(float f) {
    unsigned u;
    __builtin_memcpy(&u, &f, 4);
    u = u + 0x7FFFu + ((u >> 16) & 1u);   // RNE
    return (u16)(u >> 16);
}
__device__ __forceinline__ bf16x8 ld_frag(const u16* p) {
    union { uint4 u; bf16x8 b; } cv;
    cv.u = *(const uint4*)p;
    return cv.b;
}

// ---------------- binA: per-chunk bucket histogram (pure, 512 blocks) ---------------
__global__ __launch_bounds__(256) void binA_kernel(const int* __restrict__ dst, int E,
                                                   int* __restrict__ H, int nbuck,
                                                   int eper) {
    __shared__ int hist[512];
    int t = threadIdx.x;
    int c = blockIdx.x;
    hist[t] = 0;
    hist[t + 256] = 0;
    __syncthreads();
    int beg = c * eper, end = min(beg + eper, E);
    for (int i = beg + t; i < end; i += 256)
        atomicAdd(&hist[dst[i] >> BSHIFT], 1);
    __syncthreads();
    for (int b = t; b < nbuck; b += 256) H[c * nbuck + b] = hist[b];
}

// ---------------- tails: f32->bf16 cvt + weight transposes (1024 blocks) ------------
__global__ __launch_bounds__(256) void tail_kernel(const float* __restrict__ xf,
                                                   u16* __restrict__ xb, int total4,
                                                   const float* __restrict__ wl,
                                                   const float* __restrict__ wr,
                                                   const float* __restrict__ wres,
                                                   const float* __restrict__ wfc,
                                                   u16* __restrict__ WtL,
                                                   u16* __restrict__ WresT,
                                                   u16* __restrict__ WfcT,
                                                   int* __restrict__ row_ptr,
                                                   int N, int E) {
    int gid = blockIdx.x * 256 + threadIdx.x;
    int gstr = TGRID * 256;
    if (gid == 0) row_ptr[N] = E;
    for (int i = gid; i < total4; i += gstr) {
        float4 v = *(const float4*)(xf + i * 4);
        ushort4 o;
        o.x = f2b(v.x); o.y = f2b(v.y); o.z = f2b(v.z); o.w = f2b(v.w);
        *(ushort4*)(xb + i * 4) = o;
    }
    // W^T prep: [L][64 rows][128 cols] = concat(w_l^T, w_r^T)
    for (int idx = gid; idx < 3 * 64 * 128; idx += gstr) {
        int l = idx >> 13;
        int rem = idx & 8191;
        int n = rem >> 7;
        int k = rem & 127;
        float v = (k < 64) ? wl[l * 4096 + k * 64 + n] : wr[l * 4096 + (k - 64) * 64 + n];
        WtL[idx] = f2b(v);
    }
    for (int idx = gid; idx < 4096; idx += gstr) {
        int n = idx >> 6, k = idx & 63;
        WresT[idx] = f2b(wres[k * 64 + n]);
        WfcT[idx] = f2b(wfc[k * 64 + n]);
    }
}

// ---------------- binS2: per-bucket scan over chunk counts -> Orel + T[b] -----------
// CHUNKS=512 values scanned by 256 threads (2 per thread).
__global__ __launch_bounds__(256) void binS2_kernel(const int* __restrict__ H,
                                                    int* __restrict__ Orel,
                                                    int* __restrict__ T,
                                                    int nbuck) {
    __shared__ int ss[256];
    int b = blockIdx.x;
    int t = threadIdx.x;
    int h0 = H[(2 * t) * nbuck + b];
    int h1 = H[(2 * t + 1) * nbuck + b];
    int s = h0 + h1;
    ss[t] = s;
    __syncthreads();
    for (int off = 1; off < 256; off <<= 1) {
        int v = (t >= off) ? ss[t - off] : 0;
        __syncthreads();
        ss[t] += v;
        __syncthreads();
    }
    int excl = ss[t] - s;
    Orel[(2 * t) * nbuck + b] = excl;
    Orel[(2 * t + 1) * nbuck + b] = excl + h0;
    if (t == 255) T[b] = ss[255];
}

// ---------------- binB: scatter packed words; bucket bases from local T-scan --------
__global__ __launch_bounds__(256) void binB_kernel(const int* __restrict__ src,
                                                   const int* __restrict__ dst, int E,
                                                   const int* __restrict__ T,
                                                   const int* __restrict__ Orel,
                                                   int* __restrict__ staging,
                                                   int nbuck, int eper) {
    __shared__ int sc[512];
    __shared__ int ss[256];
    int t = threadIdx.x;
    int c = blockIdx.x;
    int v0 = (2 * t < nbuck) ? T[2 * t] : 0;
    int v1 = (2 * t + 1 < nbuck) ? T[2 * t + 1] : 0;
    int s = v0 + v1;
    ss[t] = s;
    __syncthreads();
    for (int off = 1; off < 256; off <<= 1) {
        int u = (t >= off) ? ss[t - off] : 0;
        __syncthreads();
        ss[t] += u;
        __syncthreads();
    }
    int base0 = ss[t] - s;              // exclusive base of bucket 2t
    int o0 = (2 * t < nbuck) ? Orel[c * nbuck + 2 * t] : 0;
    int o1 = (2 * t + 1 < nbuck) ? Orel[c * nbuck + 2 * t + 1] : 0;
    sc[2 * t] = base0 + o0;
    sc[2 * t + 1] = base0 + v0 + o1;
    __syncthreads();
    int beg = c * eper, end = min(beg + eper, E);
    const int mask = (1 << BSHIFT) - 1;
    for (int i = beg + t; i < end; i += 256) {
        int d = dst[i];
        int b = d >> BSHIFT;
        int p = atomicAdd(&sc[b], 1);
        staging[p] = src[i] | ((d & mask) << 17);
    }
}

// ---------------- binC: per-bucket degree hist + scan + col scatter (LDS only) ------
__global__ __launch_bounds__(256) void binC_kernel(const int* __restrict__ staging,
                                                   const int* __restrict__ T,
                                                   int* __restrict__ row_ptr,
                                                   float* __restrict__ inv_deg,
                                                   int* __restrict__ col, int N, int nbuck) {
    __shared__ int cnt[256];
    __shared__ int lrp[256];
    __shared__ int sm[256];
    __shared__ int span[2];
    int b = blockIdx.x;
    int t = threadIdx.x;
    // bucket base via 2-per-thread scan of T
    int v0 = (2 * t < nbuck) ? T[2 * t] : 0;
    int v1 = (2 * t + 1 < nbuck) ? T[2 * t + 1] : 0;
    int s = v0 + v1;
    sm[t] = s;
    __syncthreads();
    for (int off = 1; off < 256; off <<= 1) {
        int u = (t >= off) ? sm[t - off] : 0;
        __syncthreads();
        sm[t] += u;
        __syncthreads();
    }
    int base0 = sm[t] - s;
    if (2 * t == b)     { span[0] = base0;       span[1] = base0 + v0; }
    if (2 * t + 1 == b) { span[0] = base0 + v0;  span[1] = base0 + v0 + v1; }
    cnt[t] = 0;
    __syncthreads();
    int sbeg = span[0], send = span[1];
    int node0 = b << BSHIFT;
    int nn = min(1 << BSHIFT, N - node0);
    for (int i = sbeg + t; i < send; i += 256)
        atomicAdd(&cnt[staging[i] >> 17], 1);
    __syncthreads();
    int c0 = cnt[t];
    sm[t] = c0;
    __syncthreads();
    for (int off = 1; off < 256; off <<= 1) {
        int u = (t >= off) ? sm[t - off] : 0;
        __syncthreads();
        sm[t] += u;
        __syncthreads();
    }
    lrp[t] = sm[t] - c0;   // exclusive
    __syncthreads();
    if (t < nn) {
        row_ptr[node0 + t] = sbeg + lrp[t];
        inv_deg[node0 + t] = c0 > 0 ? 1.0f / (float)c0 : 0.0f;
    }
    __syncthreads();
    for (int i = sbeg + t; i < send; i += 256) {
        int word = staging[i];
        int ld = word >> 17;
        int k = atomicSub(&cnt[ld], 1) - 1;
        col[sbeg + lrp[ld] + k] = word & 0x1FFFF;
    }
}

// ---------------- fused SAGE layer: gather-mean + GEMM + LN + ReLU + residual --------
// R9 static-slot gather (best measured) + tile edge-list staged to LDS (lcol):
// the tile's col range [rp[0],rp[64]) is contiguous -> coalesced load, then gather
// reads indices from LDS instead of dependent global col loads. Fallback to global
// col for the rare tile with >CCAP edges (uniform branch).
__global__ __launch_bounds__(256, 4) void layer_kernel(const u16* __restrict__ xb_in,
                                                       const int* __restrict__ row_ptr,
                                                       const int* __restrict__ col,
                                                       const float* __restrict__ inv_deg,
                                                       const u16* __restrict__ Wt,    // [64][128]
                                                       const float* __restrict__ bl,
                                                       const float* __restrict__ gam,
                                                       const float* __restrict__ bet,
                                                       const u16* __restrict__ WresT, // [64][64]
                                                       const float* __restrict__ bres,
                                                       const u16* __restrict__ WfcT,  // [64][64]
                                                       const float* __restrict__ bfc,
                                                       u16* __restrict__ xb_out,
                                                       float* __restrict__ fout,
                                                       int N, int layer0, int final_) {
    __shared__ __align__(16) u16 sA[64 * LPITCH];
    __shared__ __align__(16) u16 sB[64 * LPITCH];   // weights; reused as f32 stage in final
    __shared__ int lcol[CCAP];
    __shared__ int rp[65];
    __shared__ float ideg[64];
    int tid = threadIdx.x;
    int base = blockIdx.x * 64;
    int lane = tid & 63;
    int w = tid >> 6;

    // stage B (W^T rows), 4 uint4 per thread
#pragma unroll
    for (int i = 0; i < 4; i++) {
        int idx = i * 256 + tid;
        int r = idx >> 4, c = idx & 15;
        *(uint4*)&sB[r * LPITCH + c * 8] = *(const uint4*)(Wt + idx * 8);
    }
    // stage x rows into sA cols 64..127, 2 uint4 per thread
#pragma unroll
    for (int i = 0; i < 2; i++) {
        int idx = i * 256 + tid;
        int r = idx >> 3, c = idx & 7;
        int node = base + r;
        uint4 v = make_uint4(0, 0, 0, 0);
        if (node < N) v = *(const uint4*)(xb_in + node * D + c * 8);
        *(uint4*)&sA[r * LPITCH + 64 + c * 8] = v;
    }
    if (tid < 65) rp[tid] = row_ptr[min(base + tid, N)];
    if (tid < 64) ideg[tid] = (base + tid < N) ? inv_deg[base + tid] : 0.f;
    __syncthreads();

    int e0 = rp[0];
    int tileE = rp[64] - e0;
    bool fits = tileE <= CCAP;
    if (fits) {
        for (int i = tid; i < tileE; i += 256) lcol[i] = col[e0 + i];
    }
    __syncthreads();

    // gather stage: slot-per-node, 2 rounds x 8 slots per wave = 16 nodes/wave
    int slot = lane >> 3;
    int chunk = lane & 7;
    auto run_gather = [&](auto LD) {
#pragma unroll
        for (int r = 0; r < 2; r++) {
            int node_l = w * 16 + r * 8 + slot;
            float a0 = 0, a1 = 0, a2 = 0, a3 = 0, a4 = 0, a5 = 0, a6 = 0, a7 = 0;
            int e = rp[node_l], end = rp[node_l + 1];
#define ACC(v)                                          \
    a0 += u2f_lo(v.x); a1 += u2f_hi(v.x);               \
    a2 += u2f_lo(v.y); a3 += u2f_hi(v.y);               \
    a4 += u2f_lo(v.z); a5 += u2f_hi(v.z);               \
    a6 += u2f_lo(v.w); a7 += u2f_hi(v.w);
            for (; e + 7 < end; e += 8) {
                int s0 = LD(e),     s1 = LD(e + 1), s2 = LD(e + 2), s3 = LD(e + 3);
                int s4 = LD(e + 4), s5 = LD(e + 5), s6 = LD(e + 6), s7 = LD(e + 7);
                uint4 v0 = *(const uint4*)(xb_in + s0 * D + chunk * 8);
                uint4 v1 = *(const uint4*)(xb_in + s1 * D + chunk * 8);
                uint4 v2 = *(const uint4*)(xb_in + s2 * D + chunk * 8);
                uint4 v3 = *(const uint4*)(xb_in + s3 * D + chunk * 8);
                uint4 v4 = *(const uint4*)(xb_in + s4 * D + chunk * 8);
                uint4 v5 = *(const uint4*)(xb_in + s5 * D + chunk * 8);
                uint4 v6 = *(const uint4*)(xb_in + s6 * D + chunk * 8);
                uint4 v7 = *(const uint4*)(xb_in + s7 * D + chunk * 8);
                ACC(v0) ACC(v1) ACC(v2) ACC(v3)
                ACC(v4) ACC(v5) ACC(v6) ACC(v7)
            }
            if (e + 3 < end) {
                int s0 = LD(e), s1 = LD(e + 1), s2 = LD(e + 2), s3 = LD(e + 3);
                uint4 v0 = *(const uint4*)(xb_in + s0 * D + chunk * 8);
                uint4 v1 = *(const uint4*)(xb_in + s1 * D + chunk * 8);
                uint4 v2 = *(const uint4*)(xb_in + s2 * D + chunk * 8);
                uint4 v3 = *(const uint4*)(xb_in + s3 * D + chunk * 8);
                ACC(v0) ACC(v1) ACC(v2) ACC(v3)
                e += 4;
            }
            if (e + 1 < end) {
                int s0 = LD(e), s1 = LD(e + 1);
                uint4 v0 = *(const uint4*)(xb_in + s0 * D + chunk * 8);
                uint4 v1 = *(const uint4*)(xb_in + s1 * D + chunk * 8);
                ACC(v0) ACC(v1)
                e += 2;
            }
            if (e < end) {
                int s0 = LD(e);
                uint4 v0 = *(const uint4*)(xb_in + s0 * D + chunk * 8);
                ACC(v0)
            }
#undef ACC
            float m = ideg[node_l];
            uint4 o;
            o.x = (unsigned)f2b(a0 * m) | ((unsigned)f2b(a1 * m) << 16);
            o.y = (unsigned)f2b(a2 * m) | ((unsigned)f2b(a3 * m) << 16);
            o.z = (unsigned)f2b(a4 * m) | ((unsigned)f2b(a5 * m) << 16);
            o.w = (unsigned)f2b(a6 * m) | ((unsigned)f2b(a7 * m) << 16);
            *(uint4*)&sA[node_l * LPITCH + chunk * 8] = o;
        }
    };
    if (fits) run_gather([&](int e) { return lcol[e - e0]; });
    else      run_gather([&](int e) { return col[e]; });
    __syncthreads();

    // GEMM stage
    int q = lane >> 4;
    int ln = lane & 15;
    f32x4 acc[4] = {{0, 0, 0, 0}, {0, 0, 0, 0}, {0, 0, 0, 0}, {0, 0, 0, 0}};
    f32x4 accr[4] = {{0, 0, 0, 0}, {0, 0, 0, 0}, {0, 0, 0, 0}, {0, 0, 0, 0}};
    const u16* aRow = &sA[(w * 16 + ln) * LPITCH];

#pragma unroll
    for (int c = 0; c < 4; c++) {       // K = 128
        bf16x8 a = ld_frag(&aRow[c * 32 + q * 8]);
#pragma unroll
        for (int t = 0; t < 4; t++) {
            bf16x8 b = ld_frag(&sB[(t * 16 + ln) * LPITCH + c * 32 + q * 8]);
            acc[t] = __builtin_amdgcn_mfma_f32_16x16x32_bf16(a, b, acc[t], 0, 0, 0);
        }
    }
    if (layer0) {                       // residual = x @ w_res (one-shot global loads)
#pragma unroll
        for (int c = 0; c < 2; c++) {
            bf16x8 a = ld_frag(&aRow[64 + c * 32 + q * 8]);
#pragma unroll
            for (int t = 0; t < 4; t++) {
                bf16x8 b = ld_frag(WresT + (t * 16 + ln) * 64 + c * 32 + q * 8);
                accr[t] = __builtin_amdgcn_mfma_f32_16x16x32_bf16(a, b, accr[t], 0, 0, 0);
            }
        }
    }

    float bcol[4], gcol[4], btcol[4], brcol[4];
#pragma unroll
    for (int t = 0; t < 4; t++) {
        int colI = t * 16 + ln;
        bcol[t] = bl[colI];
        gcol[t] = gam[colI];
        btcol[t] = bet[colI];
        brcol[t] = layer0 ? bres[colI] : 0.f;
    }
#pragma unroll
    for (int t = 0; t < 4; t++)
#pragma unroll
        for (int r = 0; r < 4; r++) acc[t][r] += bcol[t];

    float ps[4], pq[4];
#pragma unroll
    for (int r = 0; r < 4; r++) {
        float s = 0, s2 = 0;
#pragma unroll
        for (int t = 0; t < 4; t++) { float h = acc[t][r]; s += h; s2 += h * h; }
        ps[r] = s; pq[r] = s2;
    }
    for (int off = 1; off < 16; off <<= 1) {
#pragma unroll
        for (int r = 0; r < 4; r++) {
            ps[r] += __shfl_xor(ps[r], off, 64);
            pq[r] += __shfl_xor(pq[r], off, 64);
        }
    }
    // epilogue -> sA cols 0..63 (wave-local rows; in-wave LDS dep, no barrier)
#pragma unroll
    for (int r = 0; r < 4; r++) {
        int nb = w * 16 + q * 4 + r;
        float mu = ps[r] * (1.f / 64.f);
        float var = pq[r] * (1.f / 64.f) - mu * mu;
        var = var < 0.f ? 0.f : var;
        float rstd = rsqrtf(var + 1e-5f);
#pragma unroll
        for (int t = 0; t < 4; t++) {
            int colI = t * 16 + ln;
            float hn = (acc[t][r] - mu) * rstd * gcol[t] + btcol[t];
            hn = hn > 0.f ? hn : 0.f;
            float res = layer0 ? (accr[t][r] + brcol[t])
                               : b2f(sA[nb * LPITCH + 64 + colI]);
            sA[nb * LPITCH + colI] = f2b(hn + res);
        }
    }

    if (final_) {
        // FC: out = x3 @ w_fc + b_fc; stage f32 through sB (dead after GEMM) for
        // coalesced float4 writeback. Pitch 68 floats breaks bank aliasing.
        f32x4 accf[4] = {{0, 0, 0, 0}, {0, 0, 0, 0}, {0, 0, 0, 0}, {0, 0, 0, 0}};
#pragma unroll
        for (int c = 0; c < 2; c++) {
            bf16x8 a = ld_frag(&aRow[c * 32 + q * 8]);
#pragma unroll
            for (int t = 0; t < 4; t++) {
                bf16x8 b = ld_frag(WfcT + (t * 16 + ln) * 64 + c * 32 + q * 8);
                accf[t] = __builtin_amdgcn_mfma_f32_16x16x32_bf16(a, b, accf[t], 0, 0, 0);
            }
        }
        __syncthreads();               // all waves done reading sB
        float* fB = (float*)sB;        // 64 rows x pitch 68 = 4352 floats = 17408 B
#pragma unroll
        for (int r = 0; r < 4; r++) {
            int nb = w * 16 + q * 4 + r;
#pragma unroll
            for (int t = 0; t < 4; t++) {
                int colI = t * 16 + ln;
                fB[nb * 68 + colI] = accf[t][r] + bfc[colI];
            }
        }
        __syncthreads();
#pragma unroll
        for (int i = 0; i < 4; i++) {
            int idx = i * 256 + tid;
            int row = idx >> 4, cc = idx & 15;
            int node = base + row;
            if (node < N)
                *(float4*)(fout + node * D + cc * 4) = *(const float4*)&fB[row * 68 + cc * 4];
        }
    } else {
        // coalesced writeback of this wave's 16 rows (2 uint4 per thread)
#pragma unroll
        for (int i = 0; i < 2; i++) {
            int idx = i * 64 + lane;
            int row = w * 16 + (idx >> 3);
            int ch = idx & 7;
            int node = base + row;
            if (node < N)
                *(uint4*)(xb_out + node * D + ch * 8) = *(const uint4*)&sA[row * LPITCH + ch * 8];
        }
    }
}

extern "C" void kernel_launch(void* const* d_in, const int* in_sizes, int n_in,
                              void* d_out, int out_size, void* d_ws, size_t ws_size,
                              hipStream_t stream) {
    const float* x_in = (const float*)d_in[0];
    const int* e_src = (const int*)d_in[1];
    const int* e_dst = (const int*)d_in[2];
    const float* w_l = (const float*)d_in[3];
    const float* b_l = (const float*)d_in[4];
    const float* w_r = (const float*)d_in[5];
    const float* gam = (const float*)d_in[6];
    const float* bet = (const float*)d_in[7];
    const float* w_res = (const float*)d_in[8];
    const float* b_res = (const float*)d_in[9];
    const float* w_fc = (const float*)d_in[10];
    const float* b_fc = (const float*)d_in[11];
    float* out = (float*)d_out;

    const int N = in_sizes[0] / D;
    const int E = in_sizes[1];
    const int nbuck = ((N - 1) >> BSHIFT) + 1;   // 391 for N=100000 (<=512)
    const int eper = (E + CHUNKS - 1) / CHUNKS;

    size_t o = 0;
    auto carve = [&](size_t bytes) {
        size_t cur = o;
        o += (bytes + 255) & ~(size_t)255;
        return (char*)d_ws + cur;
    };
    int* row_ptr = (int*)carve((size_t)(N + 1) * 4);
    float* inv_deg = (float*)carve((size_t)N * 4);
    int* colA = (int*)carve((size_t)E * 4);
    int* staging = (int*)carve((size_t)E * 4);
    int* Hh = (int*)carve((size_t)CHUNKS * nbuck * 4);
    int* Orel = (int*)carve((size_t)CHUNKS * nbuck * 4);
    int* Tb = (int*)carve((size_t)nbuck * 4);
    u16* WtL = (u16*)carve(3 * 64 * 128 * 2);
    u16* WresT = (u16*)carve(64 * 64 * 2);
    u16* WfcT = (u16*)carve(64 * 64 * 2);
    u16* xbA = (u16*)carve((size_t)N * D * 2);
    u16* xbB = (u16*)carve((size_t)N * D * 2);

    // CSR build (binned, LDS-atomics only) at 2-4 blocks/CU everywhere
    binA_kernel<<<CHUNKS, 256, 0, stream>>>(e_dst, E, Hh, nbuck, eper);
    tail_kernel<<<TGRID, 256, 0, stream>>>(x_in, xbA, N * D / 4,
                                           w_l, w_r, w_res, w_fc, WtL, WresT, WfcT,
                                           row_ptr, N, E);
    binS2_kernel<<<nbuck, 256, 0, stream>>>(Hh, Orel, Tb, nbuck);
    binB_kernel<<<CHUNKS, 256, 0, stream>>>(e_src, e_dst, E, Tb, Orel, staging,
                                            nbuck, eper);
    binC_kernel<<<nbuck, 256, 0, stream>>>(staging, Tb, row_ptr, inv_deg, colA, N, nbuck);

    int gridT = (N + 63) / 64;

    // layer 0: xbA -> xbB  (residual via w_res MFMA)
    layer_kernel<<<gridT, 256, 0, stream>>>(xbA, row_ptr, colA, inv_deg, WtL,
                                            b_l, gam, bet, WresT, b_res,
                                            WfcT, b_fc, xbB, out, N, 1, 0);
    // layer 1: xbB -> xbA
    layer_kernel<<<gridT, 256, 0, stream>>>(xbB, row_ptr, colA, inv_deg, WtL + 8192,
                                            b_l + 64, gam + 64, bet + 64, WresT, b_res,
                                            WfcT, b_fc, xbA, out, N, 0, 0);
    // layer 2 + fused fc: xbA -> out (f32)
    layer_kernel<<<gridT, 256, 0, stream>>>(xbA, row_ptr, colA, inv_deg, WtL + 16384,
                                            b_l + 128, gam + 128, bet + 128, WresT, b_res,
                                            WfcT, b_fc, xbB, out, N, 0, 1);
}